// Round 2
// baseline (992.784 us; speedup 1.0000x reference)
//
#include <hip/hip_runtime.h>

// ---------------- kernels ----------------

__global__ void k_init_deg(float* __restrict__ deg, int N) {
  int i = blockIdx.x * 256 + threadIdx.x;
  if (i < N) deg[i] = 1.0f;  // self-loop
}

__global__ void k_deg_edges(const int* __restrict__ dst, float* __restrict__ deg, int E) {
  int e = blockIdx.x * 256 + threadIdx.x;
  if (e < E) atomicAdd(&deg[dst[e]], 1.0f);
}

__global__ void k_dinv(float* __restrict__ deg, int N) {
  int i = blockIdx.x * 256 + threadIdx.x;
  if (i < N) deg[i] = rsqrtf(deg[i]);  // deg >= 1 always (self-loops)
}

// Y[N x C] = X[N x K] @ W[K x C], row-major. Block covers NT=16 nodes.
// 256 threads: c = tid % C, group g = tid / C handles MP = NT*C/256 nodes.
template <int K, int C>
__global__ void k_gemm(const float* __restrict__ X, const float* __restrict__ W,
                       float* __restrict__ Y, int N) {
  constexpr int NT = 16;
  constexpr int NG = 256 / C;   // node groups
  constexpr int MP = NT / NG;   // nodes per thread
  __shared__ float xs[NT * K];
  const int base = blockIdx.x * NT;
  const int tid = threadIdx.x;

  for (int i = tid; i < NT * K; i += 256) {
    int r = i / K;
    xs[i] = (base + r < N) ? X[(base + r) * K + (i % K)] : 0.0f;
  }
  __syncthreads();

  const int c = tid % C;
  const int g = tid / C;
  float acc[MP];
#pragma unroll
  for (int m = 0; m < MP; m++) acc[m] = 0.0f;

#pragma unroll 4
  for (int k = 0; k < K; k++) {
    float w = W[k * C + c];
#pragma unroll
    for (int m = 0; m < MP; m++) acc[m] += xs[(g * MP + m) * K + k] * w;
  }

#pragma unroll
  for (int m = 0; m < MP; m++) {
    int n = base + g * MP + m;
    if (n < N) Y[n * C + c] = acc[m];
  }
}

// out[i] = dinv[n]^2 * xw[i]   (self-loop term), n = i >> shiftC
__global__ void k_self_init(const float* __restrict__ xw, const float* __restrict__ dinv,
                            float* __restrict__ out, int total, int shiftC) {
  int i = blockIdx.x * 256 + threadIdx.x;
  if (i < total) {
    float dv = dinv[i >> shiftC];
    out[i] = dv * dv * xw[i];
  }
}

// one wave per edge: out[dst] += dinv[src]*dinv[dst] * xw[src]
__global__ void k_scatter(const float* __restrict__ xw, const float* __restrict__ dinv,
                          const int* __restrict__ src, const int* __restrict__ dst,
                          float* __restrict__ out, int E, int C) {
  int wid = (blockIdx.x * 256 + threadIdx.x) >> 6;
  int lane = threadIdx.x & 63;
  if (wid >= E) return;
  int s = src[wid], d = dst[wid];
  float norm = dinv[s] * dinv[d];
  const float* xr = xw + s * C;
  float* orow = out + d * C;
  for (int f = lane; f < C; f += 64) atomicAdd(&orow[f], norm * xr[f]);
}

// h[i] = relu(h[i] + b[i & (C-1)])
__global__ void k_bias_relu(float* __restrict__ h, const float* __restrict__ b,
                            int total, int cmask) {
  int i = blockIdx.x * 256 + threadIdx.x;
  if (i < total) h[i] = fmaxf(h[i] + b[i & cmask], 0.0f);
}

// counts per graph
__global__ void k_cnt(const int* __restrict__ batch, float* __restrict__ cnt, int N) {
  int i = blockIdx.x * 256 + threadIdx.x;
  if (i < N) atomicAdd(&cnt[batch[i]], 1.0f);
}

// pooled sums; batch sorted -> run-length accumulate, flush at boundaries. C=64.
__global__ void k_pool(const float* __restrict__ h, const int* __restrict__ batch,
                       float* __restrict__ sums, int N) {
  const int C = 64;
  int f = threadIdx.x & 63;
  int sub = threadIdx.x >> 6;
  int n0 = blockIdx.x * 256 + sub * 64;
  if (n0 >= N) return;
  int n1 = min(n0 + 64, N);
  int curb = batch[n0];
  float acc = 0.0f;
  for (int n = n0; n < n1; n++) {
    int b = batch[n];
    if (b != curb) {
      atomicAdd(&sums[curb * C + f], acc);
      acc = 0.0f;
      curb = b;
    }
    acc += h[n * C + f];
  }
  atomicAdd(&sums[curb * C + f], acc);
}

// out[g*C+f] = out[g*C+f]/max(cnt[g],1) + b2[f]
__global__ void k_final(float* __restrict__ out, const float* __restrict__ cnt,
                        const float* __restrict__ b2, int total, int C) {
  int i = blockIdx.x * 256 + threadIdx.x;
  if (i < total) {
    int g = i / C;
    out[i] = out[i] / fmaxf(cnt[g], 1.0f) + b2[i % C];
  }
}

// ---------------- launch ----------------

extern "C" void kernel_launch(void* const* d_in, const int* in_sizes, int n_in,
                              void* d_out, int out_size, void* d_ws, size_t ws_size,
                              hipStream_t stream) {
  const float* x     = (const float*)d_in[0];
  const int*   ei    = (const int*)d_in[1];
  const int*   batch = (const int*)d_in[2];
  const float* W1    = (const float*)d_in[3];
  const float* b1    = (const float*)d_in[4];
  const float* W2    = (const float*)d_in[5];
  const float* b2    = (const float*)d_in[6];

  const int N = in_sizes[2];       // 50000
  const int E = in_sizes[1] / 2;   // 800000
  const int DH = 128, DO = 64;
  const int* src = ei;
  const int* dstv = ei + E;

  float* ws   = (float*)d_ws;
  float* dinv = ws;                       // N
  float* cnt  = ws + N;                   // 64
  float* buf1 = cnt + 64;                 // N*128: xw1, then (xw2 | out2)
  float* buf2 = buf1 + (size_t)N * DH;    // N*128: out1 / h1
  float* xw2  = buf1;                     // N*64
  float* out2 = buf1 + (size_t)N * DO;    // N*64
  float* sums = (float*)d_out;            // 64*64

  // zero outputs (re-poisoned before every call)
  hipMemsetAsync(d_out, 0, (size_t)64 * DO * sizeof(float), stream);
  hipMemsetAsync(cnt, 0, 64 * sizeof(float), stream);

  // degree / norm
  k_init_deg<<<(N + 255) / 256, 256, 0, stream>>>(dinv, N);
  k_deg_edges<<<(E + 255) / 256, 256, 0, stream>>>(dstv, dinv, E);
  k_dinv<<<(N + 255) / 256, 256, 0, stream>>>(dinv, N);

  // ---- layer 1: h1 = relu(Agg(x@W1) + b1) ----
  k_gemm<128, 128><<<(N + 15) / 16, 256, 0, stream>>>(x, W1, buf1, N);
  k_self_init<<<(N * DH + 255) / 256, 256, 0, stream>>>(buf1, dinv, buf2, N * DH, 7);
  k_scatter<<<(E + 3) / 4, 256, 0, stream>>>(buf1, dinv, src, dstv, buf2, E, DH);
  k_bias_relu<<<(N * DH + 255) / 256, 256, 0, stream>>>(buf2, b1, N * DH, DH - 1);

  // ---- layer 2: out2 = Agg(h1@W2)  (b2 folded into final divide) ----
  k_gemm<128, 64><<<(N + 15) / 16, 256, 0, stream>>>(buf2, W2, xw2, N);
  k_self_init<<<(N * DO + 255) / 256, 256, 0, stream>>>(xw2, dinv, out2, N * DO, 6);
  k_scatter<<<(E + 3) / 4, 256, 0, stream>>>(xw2, dinv, src, dstv, out2, E, DO);

  // ---- pool ----
  k_cnt<<<(N + 255) / 256, 256, 0, stream>>>(batch, cnt, N);
  k_pool<<<(N + 255) / 256, 256, 0, stream>>>(out2, batch, sums, N);
  k_final<<<(64 * DO + 255) / 256, 256, 0, stream>>>(sums, cnt, b2, 64 * DO, DO);
}

// Round 3
// 511.227 us; speedup vs baseline: 1.9420x; 1.9420x over previous
//
#include <hip/hip_runtime.h>

// ---------------- CSR construction ----------------

__global__ void k_hist(const int* __restrict__ dst, int* __restrict__ cnt, int E) {
  int e = blockIdx.x * 256 + threadIdx.x;
  if (e < E) atomicAdd(&cnt[dst[e]], 1);
}

// single-block exclusive scan cnt[N] -> rowptr[N+1] (+cursor copy) + dinv = rsqrt(cnt+1)
__global__ void k_scan(const int* __restrict__ cnt, int* __restrict__ rowptr,
                       int* __restrict__ cursor, float* __restrict__ dinv, int N) {
  __shared__ int lsum[1024];
  const int tid = threadIdx.x;
  const int chunk = (N + 1023) / 1024;
  const int lo = min(tid * chunk, N), hi = min(lo + chunk, N);
  int s = 0;
  for (int i = lo; i < hi; i++) s += cnt[i];
  lsum[tid] = s;
  __syncthreads();
  for (int d = 1; d < 1024; d <<= 1) {          // Hillis-Steele inclusive scan
    int t = (tid >= d) ? lsum[tid - d] : 0;
    __syncthreads();
    lsum[tid] += t;
    __syncthreads();
  }
  int run = lsum[tid] - s;                      // exclusive offset
  for (int i = lo; i < hi; i++) {
    int c = cnt[i];
    rowptr[i] = run;
    cursor[i] = run;
    dinv[i] = rsqrtf((float)(c + 1));           // +1 self-loop, deg>=1 always
    run += c;
  }
  if (tid == 1023) rowptr[N] = lsum[1023];      // = E
}

__global__ void k_fill(const int* __restrict__ src, const int* __restrict__ dst,
                       int* __restrict__ cursor, int* __restrict__ col, int E) {
  int e = blockIdx.x * 256 + threadIdx.x;
  if (e < E) {
    int d = dst[e];
    int p = atomicAdd(&cursor[d], 1);
    col[p] = src[e];
  }
}

// ---------------- GEMM (vector ALU; fp32 has no MFMA) ----------------
// Y[N x C] = X[N x K] @ W[K x C]. Block covers NT=16 nodes.
template <int K, int C>
__global__ void k_gemm(const float* __restrict__ X, const float* __restrict__ W,
                       float* __restrict__ Y, int N) {
  constexpr int NT = 16;
  constexpr int NG = 256 / C;
  constexpr int MP = NT / NG;
  __shared__ float xs[NT * K];
  const int base = blockIdx.x * NT;
  const int tid = threadIdx.x;

  for (int i = tid; i < NT * K; i += 256) {
    int r = i / K;
    xs[i] = (base + r < N) ? X[(base + r) * K + (i % K)] : 0.0f;
  }
  __syncthreads();

  const int c = tid % C;
  const int g = tid / C;
  float acc[MP];
#pragma unroll
  for (int m = 0; m < MP; m++) acc[m] = 0.0f;

#pragma unroll 4
  for (int k = 0; k < K; k++) {
    float w = W[k * C + c];
#pragma unroll
    for (int m = 0; m < MP; m++) acc[m] += xs[(g * MP + m) * K + k] * w;
  }

#pragma unroll
  for (int m = 0; m < MP; m++) {
    int n = base + g * MP + m;
    if (n < N) Y[n * C + c] = acc[m];
  }
}

// ---------------- CSR gather-aggregate (no atomics) ----------------
// wave per node; acc init = self-loop dinv[v]^2 * xw[v]; epilogue bias+relu optional.
template <bool RELU>
__global__ void k_agg128(const float* __restrict__ xw, const float* __restrict__ dinv,
                         const int* __restrict__ rowptr, const int* __restrict__ col,
                         const float* __restrict__ bias, float* __restrict__ out, int N) {
  const int lane = threadIdx.x & 63;
  const int v = blockIdx.x * 4 + (threadIdx.x >> 6);
  if (v >= N) return;
  const float dv = dinv[v];
  const float2* __restrict__ self = (const float2*)(xw + (size_t)v * 128);
  float2 a = self[lane];
  float2 acc;
  acc.x = dv * dv * a.x;
  acc.y = dv * dv * a.y;
  const int j1 = rowptr[v + 1];
#pragma unroll 2
  for (int j = rowptr[v]; j < j1; j++) {
    int s = col[j];
    float w = dinv[s] * dv;
    float2 r = ((const float2*)(xw + (size_t)s * 128))[lane];
    acc.x += w * r.x;
    acc.y += w * r.y;
  }
  if (RELU) {
    acc.x = fmaxf(acc.x + bias[2 * lane], 0.0f);
    acc.y = fmaxf(acc.y + bias[2 * lane + 1], 0.0f);
  }
  ((float2*)(out + (size_t)v * 128))[lane] = acc;
}

__global__ void k_agg64(const float* __restrict__ xw, const float* __restrict__ dinv,
                        const int* __restrict__ rowptr, const int* __restrict__ col,
                        float* __restrict__ out, int N) {
  const int lane = threadIdx.x & 63;
  const int v = blockIdx.x * 4 + (threadIdx.x >> 6);
  if (v >= N) return;
  const float dv = dinv[v];
  float acc = dv * dv * xw[(size_t)v * 64 + lane];
  const int j1 = rowptr[v + 1];
#pragma unroll 2
  for (int j = rowptr[v]; j < j1; j++) {
    int s = col[j];
    float w = dinv[s] * dv;
    acc += w * xw[(size_t)s * 64 + lane];
  }
  out[(size_t)v * 64 + lane] = acc;
}

// ---------------- pool (sorted batch; counts fused) ----------------
__global__ void k_pool(const float* __restrict__ h, const int* __restrict__ batch,
                       float* __restrict__ sums, float* __restrict__ gcnt, int N) {
  const int C = 64;
  const int f = threadIdx.x & 63;
  const int n0 = blockIdx.x * 256 + (threadIdx.x >> 6) * 64;
  if (n0 >= N) return;
  const int n1 = min(n0 + 64, N);
  int curb = batch[n0];
  float acc = 0.0f;
  int run = 0;
  for (int n = n0; n < n1; n++) {
    int b = batch[n];
    if (b != curb) {
      atomicAdd(&sums[curb * C + f], acc);
      if (f == 0) atomicAdd(&gcnt[curb], (float)run);
      acc = 0.0f; run = 0; curb = b;
    }
    acc += h[(size_t)n * C + f];
    run++;
  }
  atomicAdd(&sums[curb * C + f], acc);
  if (f == 0) atomicAdd(&gcnt[curb], (float)run);
}

__global__ void k_final(float* __restrict__ out, const float* __restrict__ cnt,
                        const float* __restrict__ b2, int total, int C) {
  int i = blockIdx.x * 256 + threadIdx.x;
  if (i < total) {
    int g = i / C;
    out[i] = out[i] / fmaxf(cnt[g], 1.0f) + b2[i % C];
  }
}

// ---------------- launch ----------------

extern "C" void kernel_launch(void* const* d_in, const int* in_sizes, int n_in,
                              void* d_out, int out_size, void* d_ws, size_t ws_size,
                              hipStream_t stream) {
  const float* x     = (const float*)d_in[0];
  const int*   ei    = (const int*)d_in[1];
  const int*   batch = (const int*)d_in[2];
  const float* W1    = (const float*)d_in[3];
  const float* b1    = (const float*)d_in[4];
  const float* W2    = (const float*)d_in[5];
  const float* b2    = (const float*)d_in[6];

  const int N = in_sizes[2];       // 50000
  const int E = in_sizes[1] / 2;   // 800000
  const int DH = 128, DO = 64;
  const int* src  = ei;
  const int* dstv = ei + E;

  // workspace layout: buffers first (8B-aligned for float2)
  float* buf1   = (float*)d_ws;                 // N*128  (xw1; later xw2|out2)
  float* buf2   = buf1 + (size_t)N * DH;        // N*128  (h1)
  int*   cnt    = (int*)(buf2 + (size_t)N * DH);// N
  int*   rowptr = cnt + N;                      // N+1
  int*   cursor = rowptr + N + 1;               // N
  float* dinv   = (float*)(cursor + N);         // N
  float* gcnt   = dinv + N;                     // 64
  int*   col    = (int*)(gcnt + 64);            // E
  float* xw2    = buf1;                         // N*64
  float* out2   = buf1 + (size_t)N * DO;        // N*64
  float* sums   = (float*)d_out;                // 64*64

  hipMemsetAsync(cnt, 0, (size_t)N * sizeof(int), stream);
  hipMemsetAsync(gcnt, 0, 64 * sizeof(float), stream);
  hipMemsetAsync(d_out, 0, (size_t)64 * DO * sizeof(float), stream);

  const int gE = (E + 255) / 256;
  const int gN4 = (N + 3) / 4;

  // CSR by dst + dinv
  k_hist<<<gE, 256, 0, stream>>>(dstv, cnt, E);
  k_scan<<<1, 1024, 0, stream>>>(cnt, rowptr, cursor, dinv, N);
  k_fill<<<gE, 256, 0, stream>>>(src, dstv, cursor, col, E);

  // layer 1: h1 = relu(Agg(x@W1) + b1)
  k_gemm<128, 128><<<(N + 15) / 16, 256, 0, stream>>>(x, W1, buf1, N);
  k_agg128<true><<<gN4, 256, 0, stream>>>(buf1, dinv, rowptr, col, b1, buf2, N);

  // layer 2: out2 = Agg(h1@W2); b2 folded into k_final
  k_gemm<128, 64><<<(N + 15) / 16, 256, 0, stream>>>(buf2, W2, xw2, N);
  k_agg64<<<gN4, 256, 0, stream>>>(xw2, dinv, rowptr, col, out2, N);

  // pool
  k_pool<<<(N + 255) / 256, 256, 0, stream>>>(out2, batch, sums, gcnt, N);
  k_final<<<(64 * DO + 255) / 256, 256, 0, stream>>>(sums, gcnt, b2, 64 * DO, DO);
}

// Round 4
// 390.450 us; speedup vs baseline: 2.5427x; 1.3093x over previous
//
#include <hip/hip_runtime.h>

// ---------------- CSR-by-dst (order-free segments) ----------------

__global__ void k_hist(const int* __restrict__ dst, int* __restrict__ cnt, int E) {
  int e = blockIdx.x * 256 + threadIdx.x;
  if (e < E) atomicAdd(&cnt[dst[e]], 1);
}

// Allocate a contiguous segment per node in arbitrary order: wave prefix-sum of
// cnt, one atomicAdd per wave. Also computes dinv = rsqrt(deg+1).
__global__ void k_seg(const int* __restrict__ cnt, int* __restrict__ start,
                      int* __restrict__ cursor, float* __restrict__ dinv,
                      int* __restrict__ counter, int N) {
  const int v = blockIdx.x * 256 + threadIdx.x;
  const int lane = threadIdx.x & 63;
  int c = (v < N) ? cnt[v] : 0;
  int incl = c;
#pragma unroll
  for (int d = 1; d < 64; d <<= 1) {
    int t = __shfl_up(incl, d, 64);
    if (lane >= d) incl += t;
  }
  int base = 0;
  if (lane == 63) base = atomicAdd(counter, incl);
  base = __shfl(base, 63, 64);
  if (v < N) {
    int s = base + incl - c;
    start[v] = s;
    cursor[v] = s;
    dinv[v] = rsqrtf((float)(c + 1));  // +1 self-loop
  }
}

__global__ void k_fill(const int* __restrict__ src, const int* __restrict__ dst,
                       int* __restrict__ cursor, int* __restrict__ col, int E) {
  int e = blockIdx.x * 256 + threadIdx.x;
  if (e < E) {
    int d = dst[e];
    int p = atomicAdd(&cursor[d], 1);
    col[p] = src[e];
  }
}

// ---------------- GEMM (vector ALU; fp32 has no MFMA) ----------------
// Y[N x C] = X[N x K] @ W[K x C]. Block covers NT=16 nodes.
template <int K, int C>
__global__ void k_gemm(const float* __restrict__ X, const float* __restrict__ W,
                       float* __restrict__ Y, int N) {
  constexpr int NT = 16;
  constexpr int NG = 256 / C;
  constexpr int MP = NT / NG;
  __shared__ float xs[NT * K];
  const int base = blockIdx.x * NT;
  const int tid = threadIdx.x;

  for (int i = tid; i < NT * K; i += 256) {
    int r = i / K;
    xs[i] = (base + r < N) ? X[(base + r) * K + (i % K)] : 0.0f;
  }
  __syncthreads();

  const int c = tid % C;
  const int g = tid / C;
  float acc[MP];
#pragma unroll
  for (int m = 0; m < MP; m++) acc[m] = 0.0f;

#pragma unroll 4
  for (int k = 0; k < K; k++) {
    float w = W[k * C + c];
#pragma unroll
    for (int m = 0; m < MP; m++) acc[m] += xs[(g * MP + m) * K + k] * w;
  }

#pragma unroll
  for (int m = 0; m < MP; m++) {
    int n = base + g * MP + m;
    if (n < N) Y[n * C + c] = acc[m];
  }
}

// ---------------- gather-aggregate (no atomics) ----------------
// wave per node; acc init = self-loop dinv[v]^2 * xw[v]; epilogue bias+relu optional.
template <bool RELU>
__global__ void k_agg128(const float* __restrict__ xw, const float* __restrict__ dinv,
                         const int* __restrict__ start, const int* __restrict__ cnt,
                         const int* __restrict__ col, const float* __restrict__ bias,
                         float* __restrict__ out, int N) {
  const int lane = threadIdx.x & 63;
  const int v = blockIdx.x * 4 + (threadIdx.x >> 6);
  if (v >= N) return;
  const float dv = dinv[v];
  float2 a = ((const float2*)(xw + (size_t)v * 128))[lane];
  float2 acc;
  acc.x = dv * dv * a.x;
  acc.y = dv * dv * a.y;
  const int j0 = start[v];
  const int j1 = j0 + cnt[v];
#pragma unroll 2
  for (int j = j0; j < j1; j++) {
    int s = col[j];
    float w = dinv[s] * dv;
    float2 r = ((const float2*)(xw + (size_t)s * 128))[lane];
    acc.x += w * r.x;
    acc.y += w * r.y;
  }
  if (RELU) {
    acc.x = fmaxf(acc.x + bias[2 * lane], 0.0f);
    acc.y = fmaxf(acc.y + bias[2 * lane + 1], 0.0f);
  }
  ((float2*)(out + (size_t)v * 128))[lane] = acc;
}

__global__ void k_agg64(const float* __restrict__ xw, const float* __restrict__ dinv,
                        const int* __restrict__ start, const int* __restrict__ cnt,
                        const int* __restrict__ col, float* __restrict__ out, int N) {
  const int lane = threadIdx.x & 63;
  const int v = blockIdx.x * 4 + (threadIdx.x >> 6);
  if (v >= N) return;
  const float dv = dinv[v];
  float acc = dv * dv * xw[(size_t)v * 64 + lane];
  const int j0 = start[v];
  const int j1 = j0 + cnt[v];
#pragma unroll 2
  for (int j = j0; j < j1; j++) {
    int s = col[j];
    float w = dinv[s] * dv;
    acc += w * xw[(size_t)s * 64 + lane];
  }
  out[(size_t)v * 64 + lane] = acc;
}

// ---------------- pool (sorted batch; counts fused) ----------------
__global__ void k_pool(const float* __restrict__ h, const int* __restrict__ batch,
                       float* __restrict__ sums, float* __restrict__ gcnt, int N) {
  const int C = 64;
  const int f = threadIdx.x & 63;
  const int n0 = blockIdx.x * 256 + (threadIdx.x >> 6) * 64;
  if (n0 >= N) return;
  const int n1 = min(n0 + 64, N);
  int curb = batch[n0];
  float acc = 0.0f;
  int run = 0;
  for (int n = n0; n < n1; n++) {
    int b = batch[n];
    if (b != curb) {
      atomicAdd(&sums[curb * C + f], acc);
      if (f == 0) atomicAdd(&gcnt[curb], (float)run);
      acc = 0.0f; run = 0; curb = b;
    }
    acc += h[(size_t)n * C + f];
    run++;
  }
  atomicAdd(&sums[curb * C + f], acc);
  if (f == 0) atomicAdd(&gcnt[curb], (float)run);
}

__global__ void k_final(float* __restrict__ out, const float* __restrict__ cnt,
                        const float* __restrict__ b2, int total, int C) {
  int i = blockIdx.x * 256 + threadIdx.x;
  if (i < total) {
    int g = i / C;
    out[i] = out[i] / fmaxf(cnt[g], 1.0f) + b2[i % C];
  }
}

// ---------------- launch ----------------

extern "C" void kernel_launch(void* const* d_in, const int* in_sizes, int n_in,
                              void* d_out, int out_size, void* d_ws, size_t ws_size,
                              hipStream_t stream) {
  const float* x     = (const float*)d_in[0];
  const int*   ei    = (const int*)d_in[1];
  const int*   batch = (const int*)d_in[2];
  const float* W1    = (const float*)d_in[3];
  const float* b1    = (const float*)d_in[4];
  const float* W2    = (const float*)d_in[5];
  const float* b2    = (const float*)d_in[6];

  const int N = in_sizes[2];       // 50000
  const int E = in_sizes[1] / 2;   // 800000
  const int DH = 128, DO = 64;
  const int* src  = ei;
  const int* dstv = ei + E;

  // workspace layout (8B-aligned buffers first)
  float* buf1    = (float*)d_ws;                  // N*128  (xw1; later xw2|out2)
  float* buf2    = buf1 + (size_t)N * DH;         // N*128  (h1)
  int*   cnt     = (int*)(buf2 + (size_t)N * DH); // N
  int*   startv  = cnt + N;                       // N
  int*   cursor  = startv + N;                    // N
  int*   counter = cursor + N;                    // 1
  float* dinv    = (float*)(counter + 1);         // N
  float* gcnt    = dinv + N;                      // 64
  int*   col     = (int*)(gcnt + 64);             // E
  float* xw2     = buf1;                          // N*64
  float* out2    = buf1 + (size_t)N * DO;         // N*64
  float* sums    = (float*)d_out;                 // 64*64

  hipMemsetAsync(cnt, 0, (size_t)(N + 3 * N + 1) * 0 + (size_t)N * sizeof(int), stream);
  hipMemsetAsync(counter, 0, sizeof(int), stream);
  hipMemsetAsync(gcnt, 0, 64 * sizeof(float), stream);
  hipMemsetAsync(d_out, 0, (size_t)64 * DO * sizeof(float), stream);

  const int gE = (E + 255) / 256;
  const int gN = (N + 255) / 256;
  const int gN4 = (N + 3) / 4;

  // segments by dst + dinv
  k_hist<<<gE, 256, 0, stream>>>(dstv, cnt, E);
  k_seg<<<gN, 256, 0, stream>>>(cnt, startv, cursor, dinv, counter, N);
  k_fill<<<gE, 256, 0, stream>>>(src, dstv, cursor, col, E);

  // layer 1: h1 = relu(Agg(x@W1) + b1)
  k_gemm<128, 128><<<(N + 15) / 16, 256, 0, stream>>>(x, W1, buf1, N);
  k_agg128<true><<<gN4, 256, 0, stream>>>(buf1, dinv, startv, cnt, col, b1, buf2, N);

  // layer 2: out2 = Agg(h1@W2); b2 folded into k_final
  k_gemm<128, 64><<<(N + 15) / 16, 256, 0, stream>>>(buf2, W2, xw2, N);
  k_agg64<<<gN4, 256, 0, stream>>>(xw2, dinv, startv, cnt, col, out2, N);

  // pool
  k_pool<<<gN, 256, 0, stream>>>(out2, batch, sums, gcnt, N);
  k_final<<<(64 * DO + 255) / 256, 256, 0, stream>>>(sums, gcnt, b2, 64 * DO, DO);
}

// Round 5
// 333.646 us; speedup vs baseline: 2.9756x; 1.1703x over previous
//
#include <hip/hip_runtime.h>

typedef __attribute__((ext_vector_type(8))) short bf16x8;
typedef __attribute__((ext_vector_type(4))) float f32x4;

__device__ __forceinline__ unsigned short f2bf(float f) {  // RNE
  unsigned u = __float_as_uint(f);
  u += 0x7FFFu + ((u >> 16) & 1u);
  return (unsigned short)(u >> 16);
}
__device__ __forceinline__ float bflo(unsigned u) { return __uint_as_float(u << 16); }
__device__ __forceinline__ float bfhi(unsigned u) { return __uint_as_float(u & 0xFFFF0000u); }
__device__ __forceinline__ float bf1(unsigned short h) { return __uint_as_float(((unsigned)h) << 16); }

// ---------------- segment construction (CSR-by-dst, order-free) ----------------

__global__ void k_hist(const int* __restrict__ dst, int* __restrict__ cnt, int E) {
  int e = blockIdx.x * 256 + threadIdx.x;
  if (e < E) atomicAdd(&cnt[dst[e]], 1);
}

__global__ void k_seg(const int* __restrict__ cnt, int* __restrict__ start,
                      int* __restrict__ cursor, float* __restrict__ dinv,
                      int* __restrict__ counter, int N) {
  const int v = blockIdx.x * 256 + threadIdx.x;
  const int lane = threadIdx.x & 63;
  int c = (v < N) ? cnt[v] : 0;
  int incl = c;
#pragma unroll
  for (int d = 1; d < 64; d <<= 1) {
    int t = __shfl_up(incl, d, 64);
    if (lane >= d) incl += t;
  }
  int base = 0;
  if (lane == 63) base = atomicAdd(counter, incl);
  base = __shfl(base, 63, 64);
  if (v < N) {
    int s = base + incl - c;
    start[v] = s;
    cursor[v] = s;
    dinv[v] = rsqrtf((float)(c + 1));  // +1 self-loop
  }
}

__global__ void k_fill(const int* __restrict__ src, const int* __restrict__ dst,
                       int* __restrict__ cursor, int* __restrict__ col, int E) {
  int e = blockIdx.x * 256 + threadIdx.x;
  if (e < E) {
    int d = dst[e];
    int p = atomicAdd(&cursor[d], 1);
    col[p] = src[e];
  }
}

// ---------------- MFMA bf16 GEMM: Y(bf16)[N x CO] = A[N x 128] @ W(f32->bf16)[128 x CO] ----
// mfma_f32_16x16x32_bf16 layouts (m89/m91-verified):
//   A: m=lane&15, k=quad*8+j   B: n=lane&15, k=quad*8+j   D: col=lane&15, row=quad*4+reg
template <int CO, bool AF32>
__global__ __launch_bounds__(256) void k_gemm_mfma(const void* __restrict__ Aptr,
                                                   const float* __restrict__ W,
                                                   unsigned short* __restrict__ Y, int N) {
  constexpr int K = 128;
  constexpr int SP = K + 8;  // padded LDS row stride (shorts); 272B = 17*16B (b128-aligned)
  __shared__ unsigned short Wl[CO * SP];
  const int tid = threadIdx.x;

  // stage W transposed as bf16: Wl[n][k]
  for (int i = tid; i < K * CO; i += 256) {
    int k = i / CO, n = i % CO;
    Wl[n * SP + k] = f2bf(W[i]);
  }
  __syncthreads();

  const int lane = tid & 63;
  const int quad = lane >> 4, l16 = lane & 15;
  const int mbase = blockIdx.x * 64 + (tid >> 6) * 16;
  const int arow = min(mbase + l16, N - 1);

  bf16x8 afrag[4];
  if constexpr (AF32) {
    const float* A = (const float*)Aptr + (size_t)arow * K;
#pragma unroll
    for (int ks = 0; ks < 4; ks++) {
      const float4* p = (const float4*)(A + ks * 32 + quad * 8);
      float4 f0 = p[0], f1 = p[1];
      afrag[ks] = (bf16x8){(short)f2bf(f0.x), (short)f2bf(f0.y), (short)f2bf(f0.z), (short)f2bf(f0.w),
                           (short)f2bf(f1.x), (short)f2bf(f1.y), (short)f2bf(f1.z), (short)f2bf(f1.w)};
    }
  } else {
    const unsigned short* A = (const unsigned short*)Aptr + (size_t)arow * K;
#pragma unroll
    for (int ks = 0; ks < 4; ks++) afrag[ks] = *(const bf16x8*)(A + ks * 32 + quad * 8);
  }

#pragma unroll
  for (int ct = 0; ct < CO / 16; ct++) {
    f32x4 acc = {0.0f, 0.0f, 0.0f, 0.0f};
#pragma unroll
    for (int ks = 0; ks < 4; ks++) {
      bf16x8 b = *(const bf16x8*)(&Wl[(ct * 16 + l16) * SP + ks * 32 + quad * 8]);
      acc = __builtin_amdgcn_mfma_f32_16x16x32_bf16(afrag[ks], b, acc, 0, 0, 0);
    }
#pragma unroll
    for (int reg = 0; reg < 4; reg++) {
      int node = mbase + quad * 4 + reg;
      if (node < N) Y[(size_t)node * CO + ct * 16 + l16] = f2bf(acc[reg]);
    }
  }
}

// ---------------- gather-aggregate (bf16 rows, fp32 accumulate) ----------------
// wave per node; acc init = dinv[v]^2 * xw[v]; layer1: +bias, relu, bf16 out.
__global__ void k_agg128(const unsigned short* __restrict__ xwb, const float* __restrict__ dinv,
                         const int* __restrict__ start, const int* __restrict__ cnt,
                         const int* __restrict__ col, const float* __restrict__ bias,
                         unsigned short* __restrict__ h1b, int N) {
  const int lane = threadIdx.x & 63;
  const int v = blockIdx.x * 4 + (threadIdx.x >> 6);
  if (v >= N) return;
  const float dv = dinv[v];
  unsigned u = ((const unsigned*)(xwb + (size_t)v * 128))[lane];
  float ax = dv * dv * bflo(u);
  float ay = dv * dv * bfhi(u);
  const int j0 = start[v];
  const int j1 = j0 + cnt[v];
#pragma unroll 2
  for (int j = j0; j < j1; j++) {
    int s = col[j];
    float w = dinv[s] * dv;
    unsigned r = ((const unsigned*)(xwb + (size_t)s * 128))[lane];
    ax += w * bflo(r);
    ay += w * bfhi(r);
  }
  float2 b = ((const float2*)bias)[lane];
  ax = fmaxf(ax + b.x, 0.0f);
  ay = fmaxf(ay + b.y, 0.0f);
  ((unsigned*)(h1b + (size_t)v * 128))[lane] =
      (unsigned)f2bf(ax) | ((unsigned)f2bf(ay) << 16);
}

__global__ void k_agg64(const unsigned short* __restrict__ xwb, const float* __restrict__ dinv,
                        const int* __restrict__ start, const int* __restrict__ cnt,
                        const int* __restrict__ col, float* __restrict__ out, int N) {
  const int lane = threadIdx.x & 63;
  const int v = blockIdx.x * 4 + (threadIdx.x >> 6);
  if (v >= N) return;
  const float dv = dinv[v];
  float acc = dv * dv * bf1(xwb[(size_t)v * 64 + lane]);
  const int j0 = start[v];
  const int j1 = j0 + cnt[v];
#pragma unroll 2
  for (int j = j0; j < j1; j++) {
    int s = col[j];
    acc += dinv[s] * dv * bf1(xwb[(size_t)s * 64 + lane]);
  }
  out[(size_t)v * 64 + lane] = acc;
}

// ---------------- pool (sorted batch; counts fused) ----------------
__global__ void k_pool(const float* __restrict__ h, const int* __restrict__ batch,
                       float* __restrict__ sums, float* __restrict__ gcnt, int N) {
  const int C = 64;
  const int f = threadIdx.x & 63;
  const int n0 = blockIdx.x * 256 + (threadIdx.x >> 6) * 64;
  if (n0 >= N) return;
  const int n1 = min(n0 + 64, N);
  int curb = batch[n0];
  float acc = 0.0f;
  int run = 0;
  for (int n = n0; n < n1; n++) {
    int b = batch[n];
    if (b != curb) {
      atomicAdd(&sums[curb * C + f], acc);
      if (f == 0) atomicAdd(&gcnt[curb], (float)run);
      acc = 0.0f; run = 0; curb = b;
    }
    acc += h[(size_t)n * C + f];
    run++;
  }
  atomicAdd(&sums[curb * C + f], acc);
  if (f == 0) atomicAdd(&gcnt[curb], (float)run);
}

__global__ void k_final(float* __restrict__ out, const float* __restrict__ cnt,
                        const float* __restrict__ b2, int total, int C) {
  int i = blockIdx.x * 256 + threadIdx.x;
  if (i < total) {
    int g = i / C;
    out[i] = out[i] / fmaxf(cnt[g], 1.0f) + b2[i % C];
  }
}

// ---------------- launch ----------------

extern "C" void kernel_launch(void* const* d_in, const int* in_sizes, int n_in,
                              void* d_out, int out_size, void* d_ws, size_t ws_size,
                              hipStream_t stream) {
  const float* x     = (const float*)d_in[0];
  const int*   ei    = (const int*)d_in[1];
  const int*   batch = (const int*)d_in[2];
  const float* W1    = (const float*)d_in[3];
  const float* b1    = (const float*)d_in[4];
  const float* W2    = (const float*)d_in[5];
  const float* b2    = (const float*)d_in[6];

  const int N = in_sizes[2];       // 50000
  const int E = in_sizes[1] / 2;   // 800000
  const int* src  = ei;
  const int* dstv = ei + E;

  // workspace layout
  unsigned short* xw1b = (unsigned short*)d_ws;            // N*128 bf16 (later xw2b)
  unsigned short* h1b  = xw1b + (size_t)N * 128;           // N*128 bf16
  unsigned short* xw2b = xw1b;                             // N*64 bf16 (overlays dead xw1b)
  float* out2   = (float*)(h1b + (size_t)N * 128);         // N*64 f32
  int*   cnt    = (int*)(out2 + (size_t)N * 64);           // N
  int*   startv = cnt + N;                                 // N
  int*   cursor = startv + N;                              // N
  int*   counter= cursor + N;                              // 1
  float* dinv   = (float*)(counter + 1);                   // N
  float* gcnt   = dinv + N;                                // 64
  int*   col    = (int*)(gcnt + 64);                       // E
  float* sums   = (float*)d_out;                           // 64*64

  hipMemsetAsync(cnt, 0, (size_t)N * sizeof(int), stream);
  hipMemsetAsync(counter, 0, sizeof(int), stream);
  hipMemsetAsync(gcnt, 0, 64 * sizeof(float), stream);
  hipMemsetAsync(d_out, 0, (size_t)64 * 64 * sizeof(float), stream);

  const int gE = (E + 255) / 256;
  const int gN = (N + 255) / 256;
  const int gN4 = (N + 3) / 4;
  const int gM = (N + 63) / 64;

  // segments by dst + dinv
  k_hist<<<gE, 256, 0, stream>>>(dstv, cnt, E);
  k_seg<<<gN, 256, 0, stream>>>(cnt, startv, cursor, dinv, counter, N);
  k_fill<<<gE, 256, 0, stream>>>(src, dstv, cursor, col, E);

  // layer 1: h1 = relu(Agg(x@W1) + b1), bf16 storage throughout
  k_gemm_mfma<128, true><<<gM, 256, 0, stream>>>(x, W1, xw1b, N);
  k_agg128<<<gN4, 256, 0, stream>>>(xw1b, dinv, startv, cnt, col, b1, h1b, N);

  // layer 2: out2 = Agg(h1@W2); b2 folded into k_final
  k_gemm_mfma<64, false><<<gM, 256, 0, stream>>>(h1b, W2, xw2b, N);
  k_agg64<<<gN4, 256, 0, stream>>>(xw2b, dinv, startv, cnt, col, out2, N);

  // pool
  k_pool<<<gN, 256, 0, stream>>>(out2, batch, sums, gcnt, N);
  k_final<<<(64 * 64 + 255) / 256, 256, 0, stream>>>(sums, gcnt, b2, 64 * 64, 64);
}

// Round 6
// 305.333 us; speedup vs baseline: 3.2515x; 1.0927x over previous
//
#include <hip/hip_runtime.h>

typedef __attribute__((ext_vector_type(8))) short bf16x8;
typedef __attribute__((ext_vector_type(4))) float f32x4;

__device__ __forceinline__ unsigned short f2bf(float f) {  // RNE
  unsigned u = __float_as_uint(f);
  u += 0x7FFFu + ((u >> 16) & 1u);
  return (unsigned short)(u >> 16);
}
__device__ __forceinline__ float bflo(unsigned u) { return __uint_as_float(u << 16); }
__device__ __forceinline__ float bfhi(unsigned u) { return __uint_as_float(u & 0xFFFF0000u); }
__device__ __forceinline__ float bf1(unsigned short h) { return __uint_as_float(((unsigned)h) << 16); }

// ---------------- MFMA bf16 GEMM body (m89/m91-verified layouts) ----------------
// A: m=lane&15, k=quad*8+j   B: n=lane&15, k=quad*8+j   D: col=lane&15, row=quad*4+reg
template <int CO, bool AF32>
__device__ __forceinline__ void gemm_body(const void* __restrict__ Aptr,
                                          const float* __restrict__ W,
                                          unsigned short* __restrict__ Y, int N,
                                          int bid, int tid, unsigned short* Wl) {
  constexpr int K = 128;
  constexpr int SP = K + 8;  // padded LDS row stride (shorts)
  for (int i = tid; i < K * CO; i += 256) {
    int k = i / CO, n = i % CO;
    Wl[n * SP + k] = f2bf(W[i]);
  }
  __syncthreads();

  const int lane = tid & 63;
  const int quad = lane >> 4, l16 = lane & 15;
  const int mbase = bid * 64 + (tid >> 6) * 16;
  const int arow = min(mbase + l16, N - 1);

  bf16x8 afrag[4];
  if constexpr (AF32) {
    const float* A = (const float*)Aptr + (size_t)arow * K;
#pragma unroll
    for (int ks = 0; ks < 4; ks++) {
      const float4* p = (const float4*)(A + ks * 32 + quad * 8);
      float4 f0 = p[0], f1 = p[1];
      afrag[ks] = (bf16x8){(short)f2bf(f0.x), (short)f2bf(f0.y), (short)f2bf(f0.z), (short)f2bf(f0.w),
                           (short)f2bf(f1.x), (short)f2bf(f1.y), (short)f2bf(f1.z), (short)f2bf(f1.w)};
    }
  } else {
    const unsigned short* A = (const unsigned short*)Aptr + (size_t)arow * K;
#pragma unroll
    for (int ks = 0; ks < 4; ks++) afrag[ks] = *(const bf16x8*)(A + ks * 32 + quad * 8);
  }

#pragma unroll
  for (int ct = 0; ct < CO / 16; ct++) {
    f32x4 acc = {0.0f, 0.0f, 0.0f, 0.0f};
#pragma unroll
    for (int ks = 0; ks < 4; ks++) {
      bf16x8 b = *(const bf16x8*)(&Wl[(ct * 16 + l16) * SP + ks * 32 + quad * 8]);
      acc = __builtin_amdgcn_mfma_f32_16x16x32_bf16(afrag[ks], b, acc, 0, 0, 0);
    }
#pragma unroll
    for (int reg = 0; reg < 4; reg++) {
      int node = mbase + quad * 4 + reg;
      if (node < N) Y[(size_t)node * CO + ct * 16 + l16] = f2bf(acc[reg]);
    }
  }
}

// ---------------- mega1: GEMM1 | edge histogram | batch boundaries (independent) ----
__global__ __launch_bounds__(256) void k_mega1(const float* __restrict__ x,
                                               const float* __restrict__ W1,
                                               unsigned short* __restrict__ xw1b, int N,
                                               const int* __restrict__ dst,
                                               int* __restrict__ cnt, int E,
                                               const int* __restrict__ batch,
                                               int* __restrict__ firstIdx,
                                               int gM, int gE) {
  __shared__ unsigned short Wl[128 * 136];
  const int bid = blockIdx.x, tid = threadIdx.x;
  if (bid < gM) {
    gemm_body<128, true>(x, W1, xw1b, N, bid, tid, Wl);
  } else if (bid < gM + gE) {
    int e = (bid - gM) * 256 + tid;
    if (e < E) atomicAdd(&cnt[dst[e]], 1);
  } else {
    int n = (bid - gM - gE) * 256 + tid;
    if (n < N) {
      int b = batch[n];
      if (n == 0 || batch[n - 1] != b) firstIdx[b] = n + 1;  // first occurrence, +1-encoded
    }
  }
}

// ---------------- segment allocation (order-free) ----------------
__global__ void k_seg(const int* __restrict__ cnt, int* __restrict__ start,
                      int* __restrict__ cursor, float* __restrict__ dinv,
                      int* __restrict__ counter, int N) {
  const int v = blockIdx.x * 256 + threadIdx.x;
  const int lane = threadIdx.x & 63;
  int c = (v < N) ? cnt[v] : 0;
  int incl = c;
#pragma unroll
  for (int d = 1; d < 64; d <<= 1) {
    int t = __shfl_up(incl, d, 64);
    if (lane >= d) incl += t;
  }
  int base = 0;
  if (lane == 63) base = atomicAdd(counter, incl);
  base = __shfl(base, 63, 64);
  if (v < N) {
    int s = base + incl - c;
    start[v] = s;
    cursor[v] = s;
    dinv[v] = rsqrtf((float)(c + 1));  // +1 self-loop
  }
}

// fill packed (src, norm-weight) pairs; weight shared by both layers
__global__ void k_fill(const int* __restrict__ src, const int* __restrict__ dst,
                       const float* __restrict__ dinv, int* __restrict__ cursor,
                       int2* __restrict__ colw, int E) {
  int e = blockIdx.x * 256 + threadIdx.x;
  if (e < E) {
    int s = src[e], d = dst[e];
    float w = dinv[s] * dinv[d];
    int p = atomicAdd(&cursor[d], 1);
    colw[p] = make_int2(s, __float_as_int(w));
  }
}

// ---------------- layer-1 aggregate: lane-prefetched edges, bf16 rows ----------------
__global__ __launch_bounds__(256) void k_agg128(const unsigned short* __restrict__ xwb,
                                                const float* __restrict__ dinv,
                                                const int* __restrict__ start,
                                                const int* __restrict__ cnt,
                                                const int2* __restrict__ colw,
                                                const float* __restrict__ bias,
                                                unsigned short* __restrict__ out, int N) {
  const int lane = threadIdx.x & 63;
  const int v = blockIdx.x * 4 + (threadIdx.x >> 6);
  if (v >= N) return;
  const float dv = dinv[v];
  unsigned u = ((const unsigned*)(xwb + (size_t)v * 128))[lane];
  float ax = dv * dv * bflo(u);
  float ay = dv * dv * bfhi(u);
  const int j0 = start[v], jc = cnt[v];
  for (int base = 0; base < jc; base += 64) {
    int2 cw = (base + lane < jc) ? colw[j0 + base + lane] : make_int2(0, 0);
    const int m = min(64, jc - base);
#pragma unroll 4
    for (int t = 0; t < m; t++) {
      int s = __shfl(cw.x, t, 64);
      float w = __int_as_float(__shfl(cw.y, t, 64));
      unsigned r = ((const unsigned*)(xwb + (size_t)s * 128))[lane];
      ax += w * bflo(r);
      ay += w * bfhi(r);
    }
  }
  float2 b = ((const float2*)bias)[lane];
  ax = fmaxf(ax + b.x, 0.0f);
  ay = fmaxf(ay + b.y, 0.0f);
  ((unsigned*)(out + (size_t)v * 128))[lane] =
      (unsigned)f2bf(ax) | ((unsigned)f2bf(ay) << 16);
}

// standalone GEMM2 (h1b bf16 -> xw2b bf16)
__global__ __launch_bounds__(256) void k_gemm2(const unsigned short* __restrict__ A,
                                               const float* __restrict__ W,
                                               unsigned short* __restrict__ Y, int N) {
  __shared__ unsigned short Wl[64 * 136];
  gemm_body<64, false>(A, W, Y, N, blockIdx.x, threadIdx.x, Wl);
}

// ---------------- layer-2 aggregate fused with mean-pool accumulation ----------------
__global__ __launch_bounds__(256) void k_aggpool(const unsigned short* __restrict__ xwb,
                                                 const float* __restrict__ dinv,
                                                 const int* __restrict__ start,
                                                 const int* __restrict__ cnt,
                                                 const int2* __restrict__ colw,
                                                 const int* __restrict__ batch,
                                                 float* __restrict__ stage, int N) {
  __shared__ float red[256];
  const int lane = threadIdx.x & 63;
  const int wv = threadIdx.x >> 6;
  const int v = blockIdx.x * 4 + wv;
  float acc = 0.0f;
  int b = 0;
  if (v < N) {
    const float dv = dinv[v];
    acc = dv * dv * bf1(xwb[(size_t)v * 64 + lane]);
    const int j0 = start[v], jc = cnt[v];
    for (int base = 0; base < jc; base += 64) {
      int2 cw = (base + lane < jc) ? colw[j0 + base + lane] : make_int2(0, 0);
      const int m = min(64, jc - base);
#pragma unroll 4
      for (int t = 0; t < m; t++) {
        int s = __shfl(cw.x, t, 64);
        float w = __int_as_float(__shfl(cw.y, t, 64));
        acc += w * bf1(xwb[(size_t)s * 64 + lane]);
      }
    }
    b = batch[v];
  }
  red[threadIdx.x] = acc;
  __syncthreads();
  const int v0 = blockIdx.x * 4;
  const int b0 = batch[min(v0, N - 1)];
  const int b3 = batch[min(v0 + 3, N - 1)];
  if ((b0 == b3) && (v0 + 3 < N)) {          // sorted batch -> block-uniform graph
    if (wv == 0) {
      float t = red[lane] + red[64 + lane] + red[128 + lane] + red[192 + lane];
      atomicAdd(&stage[b0 * 64 + lane], t);
    }
  } else if (v < N) {
    atomicAdd(&stage[b * 64 + lane], acc);
  }
}

// counts from sorted-batch first indices (suffix-min), then divide + bias, write d_out
__global__ void k_final(const float* __restrict__ stage, const int* __restrict__ firstIdx,
                        const float* __restrict__ b2, float* __restrict__ out, int N) {
  __shared__ float denom[64];
  const int tid = threadIdx.x;
  if (tid < 64) {
    int raw = firstIdx[tid];
    int fi = (raw > 0) ? raw - 1 : 0x7FFFFFFF;
    int m = fi;
#pragma unroll
    for (int d = 1; d < 64; d <<= 1) {
      int t = __shfl_down(m, d, 64);
      if (tid + d < 64) m = min(m, t);
    }
    int nxtm = __shfl_down(m, 1, 64);          // min first over graphs > tid
    int nxt = (tid == 63) ? N : min(nxtm, N);
    int c = (fi == 0x7FFFFFFF) ? 0 : (nxt - fi);
    denom[tid] = fmaxf((float)c, 1.0f);
  }
  __syncthreads();
  for (int i = tid; i < 64 * 64; i += 256)
    out[i] = stage[i] / denom[i >> 6] + b2[i & 63];
}

// ---------------- launch ----------------

extern "C" void kernel_launch(void* const* d_in, const int* in_sizes, int n_in,
                              void* d_out, int out_size, void* d_ws, size_t ws_size,
                              hipStream_t stream) {
  const float* x     = (const float*)d_in[0];
  const int*   ei    = (const int*)d_in[1];
  const int*   batch = (const int*)d_in[2];
  const float* W1    = (const float*)d_in[3];
  const float* b1    = (const float*)d_in[4];
  const float* W2    = (const float*)d_in[5];
  const float* b2    = (const float*)d_in[6];

  const int N = in_sizes[2];       // 50000
  const int E = in_sizes[1] / 2;   // 800000
  const int* src  = ei;
  const int* dstv = ei + E;

  // workspace layout
  unsigned short* xw1b = (unsigned short*)d_ws;      // N*128 bf16 (xw2b overlays later)
  unsigned short* h1b  = xw1b + (size_t)N * 128;     // N*128 bf16
  unsigned short* xw2b = xw1b;                       // N*64 bf16
  // zero region (single memset): cnt[N], counter[1], firstIdx[64], stage[4096]
  int*   cnt     = (int*)(h1b + (size_t)N * 128);
  int*   counter = cnt + N;
  int*   firstIdx= counter + 1;
  float* stage   = (float*)(firstIdx + 64);          // 64*64
  // non-zeroed scratch
  int*   startv  = (int*)(stage + 4096);             // N
  int*   cursor  = startv + N;                       // N
  float* dinv    = (float*)(cursor + N);             // N
  int*   pad     = (int*)(dinv + N);                 // keep colw 8B-aligned
  int2*  colw    = (int2*)(pad + 1);                 // E pairs
  float* outp    = (float*)d_out;                    // 64*64

  hipMemsetAsync(cnt, 0, (size_t)(N + 1 + 64 + 4096) * sizeof(int), stream);

  const int gM = (N + 63) / 64;     // 782
  const int gE = (E + 255) / 256;   // 3125
  const int gN = (N + 255) / 256;   // 196
  const int gA = (N + 3) / 4;       // 12500

  // GEMM1 + histogram + batch boundaries in one launch (independent work)
  k_mega1<<<gM + gE + gN, 256, 0, stream>>>(x, W1, xw1b, N, dstv, cnt, E,
                                            batch, firstIdx, gM, gE);
  k_seg<<<gN, 256, 0, stream>>>(cnt, startv, cursor, dinv, counter, N);
  k_fill<<<gE, 256, 0, stream>>>(src, dstv, dinv, cursor, colw, E);

  // layer 1 aggregate (+bias+relu)
  k_agg128<<<gA, 256, 0, stream>>>(xw1b, dinv, startv, cnt, colw, b1, h1b, N);

  // layer 2: GEMM then aggregate fused with pooling
  k_gemm2<<<gM, 256, 0, stream>>>(h1b, W2, xw2b, N);
  k_aggpool<<<gA, 256, 0, stream>>>(xw2b, dinv, startv, cnt, colw, batch, stage, N);

  k_final<<<1, 256, 0, stream>>>(stage, firstIdx, b2, outp, N);
}